// Round 12
// baseline (834.586 us; speedup 1.0000x reference)
//
#include <hip/hip_runtime.h>
#include <hip/hip_fp16.h>

#define D 128
typedef unsigned long long ull;
typedef _Float16 half8 __attribute__((ext_vector_type(8)));
typedef _Float16 half4v __attribute__((ext_vector_type(4)));
typedef float f32x4 __attribute__((ext_vector_type(4)));

// k-permutation: quartet k4 -> LDS pos so each MFMA fragment is one ds_read_b128
#define KPOS(k4) (((k4) & ~31) + ((((k4) & 15) >> 2) << 3) + ((((k4) >> 4) & 1) << 2))

__global__ void k_zero_int(int* p, int n) {
  int i = blockIdx.x * blockDim.x + threadIdx.x;
  if (i < n) p[i] = 0;
}

__global__ void k_copy_int(const int* __restrict__ a, int* __restrict__ b, int n) {
  int i = blockIdx.x * blockDim.x + threadIdx.x;
  if (i < n) b[i] = a[i];
}

// ---- chunk-privatized degree histogram: chunk c handled ONLY by blocks with
//      blockIdx&7==c (round-robin -> one XCD), so deg8[c] lines are XCD-private.
__global__ void k_deg_count8(const int* __restrict__ ei, int* __restrict__ deg8,
                             int E, int N) {
  const int c = blockIdx.x & 7;
  const int m = blockIdx.x >> 3;
  const int nb = gridDim.x >> 3;
  const int cE = (E + 7) >> 3;
  const int base = c * cE;
  int lim = E - base;
  if (lim > cE) lim = cE;
  int* dg = deg8 + (size_t)c * N;
  for (int i = m * 256 + threadIdx.x; i < lim; i += nb * 256) {
    int d = __builtin_nontemporal_load(&ei[E + base + i]);
    atomicAdd(&dg[d], 1);
  }
}

__global__ void k_deg_reduce(const int* __restrict__ deg8, int* __restrict__ deg, int N) {
  int i = blockIdx.x * blockDim.x + threadIdx.x;
  if (i >= N) return;
  int s = 0;
#pragma unroll
  for (int c = 0; c < 8; c++) s += deg8[(size_t)c * N + i];
  deg[i] = s;
}

// ---------------- prefix sum (generic ITEMS per thread, <=256 parts) ----------------
template <int ITEMS>
__global__ void k_scan_part(const int* __restrict__ v, int* __restrict__ part, int n) {
  __shared__ int sd[256];
  int base = blockIdx.x * (256 * ITEMS) + threadIdx.x * ITEMS;
  int s = 0;
#pragma unroll
  for (int k = 0; k < ITEMS; k++) {
    int idx = base + k;
    if (idx < n) s += v[idx];
  }
  sd[threadIdx.x] = s;
  __syncthreads();
  for (int off = 128; off > 0; off >>= 1) {
    if (threadIdx.x < off) sd[threadIdx.x] += sd[threadIdx.x + off];
    __syncthreads();
  }
  if (threadIdx.x == 0) part[blockIdx.x] = sd[0];
}

__global__ void k_scan_offsets(int* __restrict__ part, int nparts,
                               int* __restrict__ outp, int n) {
  __shared__ int sd[256];
  int v = (threadIdx.x < nparts) ? part[threadIdx.x] : 0;
  sd[threadIdx.x] = v;
  __syncthreads();
  for (int off = 1; off < 256; off <<= 1) {
    int t = (threadIdx.x >= off) ? sd[threadIdx.x - off] : 0;
    __syncthreads();
    sd[threadIdx.x] += t;
    __syncthreads();
  }
  if (threadIdx.x < nparts) part[threadIdx.x] = sd[threadIdx.x] - v;  // exclusive
  if (threadIdx.x == 0) outp[n] = sd[255];                            // total
}

template <int ITEMS>
__global__ void k_scan_final(const int* __restrict__ v, const int* __restrict__ part,
                             int* __restrict__ outp, int n) {
  __shared__ int sd[256];
  int base = blockIdx.x * (256 * ITEMS) + threadIdx.x * ITEMS;
  int loc[ITEMS];
  int s = 0;
#pragma unroll
  for (int k = 0; k < ITEMS; k++) {
    int idx = base + k;
    loc[k] = (idx < n) ? v[idx] : 0;
    s += loc[k];
  }
  sd[threadIdx.x] = s;
  __syncthreads();
  for (int off = 1; off < 256; off <<= 1) {
    int t = (threadIdx.x >= off) ? sd[threadIdx.x - off] : 0;
    __syncthreads();
    sd[threadIdx.x] += t;
    __syncthreads();
  }
  int run = part[blockIdx.x] + sd[threadIdx.x] - s;  // exclusive offset
#pragma unroll
  for (int k = 0; k < ITEMS; k++) {
    int idx = base + k;
    if (idx < n) {
      outp[idx] = run;
      run += loc[k];
    }
  }
}

// dinv = rsqrt(in_deg + 1 self-loop)
__global__ void k_dinv(const int* __restrict__ deg, float* __restrict__ dinv, int n) {
  int i = blockIdx.x * blockDim.x + threadIdx.x;
  if (i < n) dinv[i] = rsqrtf((float)deg[i] + 1.0f);
}

// stage-1 fill: chunk c (blocks with blockIdx&7==c -> one XCD) reads ONLY its 1/8
// of edges and writes ONLY its private contiguous csr8 region [S[c*N], S[(c+1)*N]).
// Minimal streaming through that L2 -> scattered writes can accumulate.
__global__ void k_fill8(const int* __restrict__ ei, int* __restrict__ cursor8,
                        int* __restrict__ csr8, int E, int N) {
  const int c = blockIdx.x & 7;
  const int m = blockIdx.x >> 3;
  const int nb = gridDim.x >> 3;
  const int cE = (E + 7) >> 3;
  const int base = c * cE;
  int lim = E - base;
  if (lim > cE) lim = cE;
  int* cur = cursor8 + (size_t)c * N;
  for (int i = m * 256 + threadIdx.x; i < lim; i += nb * 256) {
    int d = __builtin_nontemporal_load(&ei[E + base + i]);
    int s = __builtin_nontemporal_load(&ei[base + i]);
    int pos = atomicAdd(&cur[d], 1);
    csr8[pos] = s;
  }
}

// stage-2: gather node v's 8 chunk-segments into unified csr[rowptr[v]..) (node-major).
// No atomics; writes sequential per node.
__global__ void k_reorder(const int* __restrict__ S, const int* __restrict__ rowptr,
                          const int* __restrict__ csr8, int* __restrict__ csr, int N) {
  int v = blockIdx.x * blockDim.x + threadIdx.x;
  if (v >= N) return;
  int dst = rowptr[v];
#pragma unroll
  for (int c = 0; c < 8; c++) {
    int b = S[(size_t)c * N + v];
    int e = S[(size_t)c * N + v + 1];   // contiguous across chunk boundary by c-major scan
    for (int j = b; j < e; j++) csr[dst++] = __builtin_nontemporal_load(&csr8[j]);
  }
}

// ---------------- MFMA GEMM: Th[n,128](fp16) = (A[n,128] @ W[128,128]) * dinv[row] ----
template <int HALF_IN>
__launch_bounds__(256, 2)
__global__ void k_gemm_mfma(const void* __restrict__ Av, const float* __restrict__ W,
                            const float* __restrict__ dinv, __half* __restrict__ Th, int n) {
  __shared__ _Float16 Al[128 * 136];
  __shared__ _Float16 Bl[128 * 136];
  const int tid = threadIdx.x;
  const int row0 = blockIdx.x * 128;

  if (HALF_IN) {
    const _Float16* A = (const _Float16*)Av;
    for (int i = tid; i < 2048; i += 256) {
      int r = i >> 4;
      int k8 = (i & 15) << 3;
      half8 v = {0, 0, 0, 0, 0, 0, 0, 0};
      if (row0 + r < n) v = *(const half8*)&A[(size_t)(row0 + r) * D + k8];
      *(half4v*)&Al[r * 136 + KPOS(k8)]     = (half4v){v[0], v[1], v[2], v[3]};
      *(half4v*)&Al[r * 136 + KPOS(k8 + 4)] = (half4v){v[4], v[5], v[6], v[7]};
    }
  } else {
    const float* A = (const float*)Av;
    for (int i = tid; i < 4096; i += 256) {
      int r = i >> 5;
      int k4 = (i & 31) << 2;
      float4 v = make_float4(0.f, 0.f, 0.f, 0.f);
      if (row0 + r < n) v = ((const float4*)A)[(size_t)(row0 + r) * 32 + (i & 31)];
      *(half4v*)&Al[r * 136 + KPOS(k4)] =
          (half4v){(_Float16)v.x, (_Float16)v.y, (_Float16)v.z, (_Float16)v.w};
    }
  }
  for (int i = tid; i < 4096; i += 256) {
    int c = i & 127;
    int k4 = (i >> 7) << 2;
    float w0 = W[(k4 + 0) * D + c];
    float w1 = W[(k4 + 1) * D + c];
    float w2 = W[(k4 + 2) * D + c];
    float w3 = W[(k4 + 3) * D + c];
    *(half4v*)&Bl[c * 136 + KPOS(k4)] =
        (half4v){(_Float16)w0, (_Float16)w1, (_Float16)w2, (_Float16)w3};
  }
  __syncthreads();

  const int w = tid >> 6;
  const int lane = tid & 63;
  const int g = lane >> 4;
  const int q = lane & 15;

  f32x4 acc[2][8];
#pragma unroll
  for (int mt = 0; mt < 2; mt++)
#pragma unroll
    for (int nt = 0; nt < 8; nt++) acc[mt][nt] = (f32x4){0.f, 0.f, 0.f, 0.f};

#pragma unroll
  for (int kt = 0; kt < 4; kt++) {
    half8 a[2], b[8];
#pragma unroll
    for (int mt = 0; mt < 2; mt++)
      a[mt] = *(const half8*)&Al[(w * 32 + mt * 16 + q) * 136 + kt * 32 + g * 8];
#pragma unroll
    for (int nt = 0; nt < 8; nt++)
      b[nt] = *(const half8*)&Bl[(nt * 16 + q) * 136 + kt * 32 + g * 8];
#pragma unroll
    for (int mt = 0; mt < 2; mt++)
#pragma unroll
      for (int nt = 0; nt < 8; nt++)
        acc[mt][nt] = __builtin_amdgcn_mfma_f32_16x16x32_f16(a[mt], b[nt], acc[mt][nt], 0, 0, 0);
  }

#pragma unroll
  for (int mt = 0; mt < 2; mt++) {
    int baseRow = row0 + w * 32 + mt * 16 + g * 4;
    float dv[4];
#pragma unroll
    for (int r = 0; r < 4; r++) dv[r] = (baseRow + r < n) ? dinv[baseRow + r] : 0.f;
#pragma unroll
    for (int nt = 0; nt < 8; nt++) {
      int col = nt * 16 + q;
#pragma unroll
      for (int r = 0; r < 4; r++) {
        int gr = baseRow + r;
        if (gr < n) Th[(size_t)gr * D + col] = (__half)(acc[mt][nt][r] * dv[r]);
      }
    }
  }
}

// ---------------- pull-style aggregation (fp16 gathers, unroll 8) ----------------
template <int MODE>
__launch_bounds__(256)
__global__ void k_aggregate(const int* __restrict__ rowptr, const int* __restrict__ csr,
                            const float* __restrict__ dinv, const __half* __restrict__ th,
                            const float* __restrict__ b, const __half* __restrict__ resh,
                            __half* __restrict__ outh, float* __restrict__ outf, int n) {
  int node = blockIdx.x * 16 + (threadIdx.x >> 4);
  if (node >= n) return;
  const int l16 = threadIdx.x & 15;

  int beg = rowptr[node];
  int end = rowptr[node + 1];
  float dd = dinv[node];

  const float4* t4 = (const float4*)th;

  float a0, a1, a2, a3, a4, a5, a6, a7;
  {
    float4 raw = t4[(size_t)node * 16 + l16];
    const __half2* hp = (const __half2*)&raw;
    float2 f0 = __half22float2(hp[0]);
    float2 f1 = __half22float2(hp[1]);
    float2 f2 = __half22float2(hp[2]);
    float2 f3 = __half22float2(hp[3]);
    a0 = f0.x; a1 = f0.y; a2 = f1.x; a3 = f1.y;
    a4 = f2.x; a5 = f2.y; a6 = f3.x; a7 = f3.y;
  }

#define ACC_ROW(raw)                                  \
  {                                                   \
    const __half2* hp = (const __half2*)&(raw);       \
    float2 f0 = __half22float2(hp[0]);                \
    float2 f1 = __half22float2(hp[1]);                \
    float2 f2 = __half22float2(hp[2]);                \
    float2 f3 = __half22float2(hp[3]);                \
    a0 += f0.x; a1 += f0.y; a2 += f1.x; a3 += f1.y;   \
    a4 += f2.x; a5 += f2.y; a6 += f3.x; a7 += f3.y;   \
  }

  int j = beg;
  for (; j + 8 <= end; j += 8) {
    float4 r0, r1, r2, r3, r4, r5, r6, r7;
    {
      int s0 = __builtin_nontemporal_load(&csr[j + 0]);
      int s1 = __builtin_nontemporal_load(&csr[j + 1]);
      int s2 = __builtin_nontemporal_load(&csr[j + 2]);
      int s3 = __builtin_nontemporal_load(&csr[j + 3]);
      int s4 = __builtin_nontemporal_load(&csr[j + 4]);
      int s5 = __builtin_nontemporal_load(&csr[j + 5]);
      int s6 = __builtin_nontemporal_load(&csr[j + 6]);
      int s7 = __builtin_nontemporal_load(&csr[j + 7]);
      r0 = t4[(size_t)(unsigned)s0 * 16 + l16];
      r1 = t4[(size_t)(unsigned)s1 * 16 + l16];
      r2 = t4[(size_t)(unsigned)s2 * 16 + l16];
      r3 = t4[(size_t)(unsigned)s3 * 16 + l16];
      r4 = t4[(size_t)(unsigned)s4 * 16 + l16];
      r5 = t4[(size_t)(unsigned)s5 * 16 + l16];
      r6 = t4[(size_t)(unsigned)s6 * 16 + l16];
      r7 = t4[(size_t)(unsigned)s7 * 16 + l16];
    }
    ACC_ROW(r0) ACC_ROW(r1) ACC_ROW(r2) ACC_ROW(r3)
    ACC_ROW(r4) ACC_ROW(r5) ACC_ROW(r6) ACC_ROW(r7)
  }
  for (; j + 4 <= end; j += 4) {
    int s0 = __builtin_nontemporal_load(&csr[j + 0]);
    int s1 = __builtin_nontemporal_load(&csr[j + 1]);
    int s2 = __builtin_nontemporal_load(&csr[j + 2]);
    int s3 = __builtin_nontemporal_load(&csr[j + 3]);
    float4 r0 = t4[(size_t)(unsigned)s0 * 16 + l16];
    float4 r1 = t4[(size_t)(unsigned)s1 * 16 + l16];
    float4 r2 = t4[(size_t)(unsigned)s2 * 16 + l16];
    float4 r3 = t4[(size_t)(unsigned)s3 * 16 + l16];
    ACC_ROW(r0) ACC_ROW(r1) ACC_ROW(r2) ACC_ROW(r3)
  }
  for (; j < end; ++j) {
    int s = __builtin_nontemporal_load(&csr[j]);
    float4 r = t4[(size_t)(unsigned)s * 16 + l16];
    ACC_ROW(r)
  }
#undef ACC_ROW

  const float4* b4 = (const float4*)b;
  float4 bb0 = b4[l16 * 2];
  float4 bb1 = b4[l16 * 2 + 1];
  float o0 = fmaf(a0, dd, bb0.x), o1 = fmaf(a1, dd, bb0.y);
  float o2 = fmaf(a2, dd, bb0.z), o3 = fmaf(a3, dd, bb0.w);
  float o4 = fmaf(a4, dd, bb1.x), o5 = fmaf(a5, dd, bb1.y);
  float o6 = fmaf(a6, dd, bb1.z), o7 = fmaf(a7, dd, bb1.w);

  if (MODE == 1) {
    float4 raw = ((const float4*)resh)[(size_t)node * 16 + l16];
    const __half2* hp = (const __half2*)&raw;
    float2 f0 = __half22float2(hp[0]);
    float2 f1 = __half22float2(hp[1]);
    float2 f2 = __half22float2(hp[2]);
    float2 f3 = __half22float2(hp[3]);
    o0 += f0.x; o1 += f0.y; o2 += f1.x; o3 += f1.y;
    o4 += f2.x; o5 += f2.y; o6 += f3.x; o7 += f3.y;
  }
  if (MODE == 0 || MODE == 1) {
    o0 = fmaxf(o0, 0.f); o1 = fmaxf(o1, 0.f); o2 = fmaxf(o2, 0.f); o3 = fmaxf(o3, 0.f);
    o4 = fmaxf(o4, 0.f); o5 = fmaxf(o5, 0.f); o6 = fmaxf(o6, 0.f); o7 = fmaxf(o7, 0.f);
    union { __half2 h[4]; float4 f; } pk;
    pk.h[0] = __floats2half2_rn(o0, o1);
    pk.h[1] = __floats2half2_rn(o2, o3);
    pk.h[2] = __floats2half2_rn(o4, o5);
    pk.h[3] = __floats2half2_rn(o6, o7);
    ((float4*)outh)[(size_t)node * 16 + l16] = pk.f;
  } else {
    ((float4*)outf)[(size_t)node * 32 + l16 * 2] = make_float4(o0, o1, o2, o3);
    ((float4*)outf)[(size_t)node * 32 + l16 * 2 + 1] = make_float4(o4, o5, o6, o7);
  }
}

extern "C" void kernel_launch(void* const* d_in, const int* in_sizes, int n_in,
                              void* d_out, int out_size, void* d_ws, size_t ws_size,
                              hipStream_t stream) {
  const float* x  = (const float*)d_in[0];
  const int*   ei = (const int*)d_in[1];
  const float* W0 = (const float*)d_in[2];
  const float* b0 = (const float*)d_in[3];
  const float* W1 = (const float*)d_in[4];
  const float* b1 = (const float*)d_in[5];
  const float* W2 = (const float*)d_in[6];
  const float* b2 = (const float*)d_in[7];
  float* out = (float*)d_out;

  const int N = in_sizes[0] / D;   // 100000
  const int E = in_sizes[1] / 2;   // 3200000

  char* wsb = (char*)d_ws;
  auto alloc = [&](size_t bytes) {
    char* p = wsb;
    wsb += ((bytes + 255) & ~(size_t)255);
    return p;
  };
  int*    rowptr  = (int*)alloc((N + 1) * 4);
  int*    deg     = (int*)alloc(N * 4);
  int*    part    = (int*)alloc(256 * 4);
  int*    part2   = (int*)alloc(256 * 4);
  float*  dinv    = (float*)alloc(N * 4);
  int*    deg8    = (int*)alloc((size_t)8 * N * 4);
  int*    S       = (int*)alloc(((size_t)8 * N + 1) * 4);
  int*    cursor8 = (int*)alloc((size_t)8 * N * 4);
  int*    csr8    = (int*)alloc((size_t)E * 4);
  int*    csr     = (int*)alloc((size_t)E * 4);
  __half* th      = (__half*)alloc((size_t)N * D * 2);
  __half* g1h     = (__half*)alloc((size_t)N * D * 2);
  __half* g2h     = (__half*)alloc((size_t)N * D * 2);

  dim3 b256(256);
  int gN    = (N + 255) / 256;
  int gN8   = (8 * N + 255) / 256;
  int gGem  = (N + 127) / 128;
  int gAgg  = (N + 15) / 16;
  int np1   = (N + 2047) / 2048;           // ITEMS=8  -> 49 parts
  int np16  = (8 * N + 4095) / 4096;       // ITEMS=16 -> 196 parts

  // ---- CSR build (two-stage; reused by all 3 layers) ----
  k_zero_int<<<gN8, b256, 0, stream>>>(deg8, 8 * N);
  k_deg_count8<<<8 * 256, b256, 0, stream>>>(ei, deg8, E, N);
  k_deg_reduce<<<gN, b256, 0, stream>>>(deg8, deg, N);
  // rowptr = exclusive scan of deg
  k_scan_part<8><<<np1, b256, 0, stream>>>(deg, part, N);
  k_scan_offsets<<<1, b256, 0, stream>>>(part, np1, rowptr, N);
  k_scan_final<8><<<np1, b256, 0, stream>>>(deg, part, rowptr, N);
  // S = exclusive scan of deg8 (c-major, 8N elements)
  k_scan_part<16><<<np16, b256, 0, stream>>>(deg8, part2, 8 * N);
  k_scan_offsets<<<1, b256, 0, stream>>>(part2, np16, S, 8 * N);
  k_scan_final<16><<<np16, b256, 0, stream>>>(deg8, part2, S, 8 * N);
  k_dinv<<<gN, b256, 0, stream>>>(deg, dinv, N);
  k_copy_int<<<gN8, b256, 0, stream>>>(S, cursor8, 8 * N);
  k_fill8<<<8 * 256, b256, 0, stream>>>(ei, cursor8, csr8, E, N);
  k_reorder<<<gN, b256, 0, stream>>>(S, rowptr, csr8, csr, N);

  // ---- layer 0: g1 = relu(Agg(x@W0) + b0)  [fp16] ----
  k_gemm_mfma<0><<<gGem, b256, 0, stream>>>(x, W0, dinv, th, N);
  k_aggregate<0><<<gAgg, b256, 0, stream>>>(rowptr, csr, dinv, th, b0, nullptr, g1h, nullptr, N);

  // ---- layer 1: h2 = relu(Agg(g1@W1) + b1 + g1)  [fp16] ----
  k_gemm_mfma<1><<<gGem, b256, 0, stream>>>(g1h, W1, dinv, th, N);
  k_aggregate<1><<<gAgg, b256, 0, stream>>>(rowptr, csr, dinv, th, b1, g1h, g2h, nullptr, N);

  // ---- layer 2: out = Agg(h2@W2) + b2  [f32 -> d_out] ----
  k_gemm_mfma<1><<<gGem, b256, 0, stream>>>(g2h, W2, dinv, th, N);
  k_aggregate<2><<<gAgg, b256, 0, stream>>>(rowptr, csr, dinv, th, b2, nullptr, nullptr, out, N);
}

// Round 13
// 665.596 us; speedup vs baseline: 1.2539x; 1.2539x over previous
//
#include <hip/hip_runtime.h>
#include <hip/hip_fp16.h>

#define D 128
#define TILE 16384
typedef unsigned long long ull;
typedef _Float16 half8 __attribute__((ext_vector_type(8)));
typedef _Float16 half4v __attribute__((ext_vector_type(4)));
typedef float f32x4 __attribute__((ext_vector_type(4)));

// k-permutation: quartet k4 -> LDS pos so each MFMA fragment is one ds_read_b128
#define KPOS(k4) (((k4) & ~31) + ((((k4) & 15) >> 2) << 3) + ((((k4) >> 4) & 1) << 2))

// ---- 1a: per-tile bucket histogram (bucket = dst>>9), LDS only ----
__global__ void k_cnt_tiles(const int* __restrict__ ei_dst, int* __restrict__ cnt,
                            int E, int ntiles, int nb) {
  __shared__ int h[256];
  for (int i = threadIdx.x; i < nb; i += 256) h[i] = 0;
  __syncthreads();
  const int t = blockIdx.x;
  const int start = t * TILE;
  int end = start + TILE;
  if (end > E) end = E;
  for (int i = start + threadIdx.x; i < end; i += 256)
    atomicAdd(&h[__builtin_nontemporal_load(&ei_dst[i]) >> 9], 1);
  __syncthreads();
  for (int b = threadIdx.x; b < nb; b += 256)
    cnt[(size_t)b * ntiles + t] = h[b];
}

// ---- 1b: off[b][t] = base(b) + prefix over tiles; single block, no atomics ----
__global__ void k_tile_scan(const int* __restrict__ cnt, int* __restrict__ off,
                            int nb, int ntiles) {
  __shared__ int sd[256];
  int total = 0;
  if (threadIdx.x < nb) {
    const int* row = cnt + (size_t)threadIdx.x * ntiles;
    for (int t = 0; t < ntiles; t++) total += row[t];
  }
  sd[threadIdx.x] = total;
  __syncthreads();
  for (int o = 1; o < 256; o <<= 1) {
    int v = (threadIdx.x >= o) ? sd[threadIdx.x - o] : 0;
    __syncthreads();
    sd[threadIdx.x] += v;
    __syncthreads();
  }
  int base = sd[threadIdx.x] - total;  // exclusive
  if (threadIdx.x < nb) {
    const int* row = cnt + (size_t)threadIdx.x * ntiles;
    int* orow = off + (size_t)threadIdx.x * ntiles;
    int run = base;
    for (int t = 0; t < ntiles; t++) { orow[t] = run; run += row[t]; }
  }
}

// ---- 1c: scatter edges into bucket-major runs (LDS rank, no global atomics) ----
__global__ void k_scatter_bucket(const int* __restrict__ ei, const int* __restrict__ off,
                                 ull* __restrict__ ebb, int E, int ntiles, int nb) {
  __shared__ int h[256];
  __shared__ int base[256];
  const int t = blockIdx.x;
  for (int i = threadIdx.x; i < nb; i += 256) {
    h[i] = 0;
    base[i] = off[(size_t)i * ntiles + t];
  }
  __syncthreads();
  const int start = t * TILE;
  int end = start + TILE;
  if (end > E) end = E;
  for (int i = start + threadIdx.x; i < end; i += 256) {
    int d = __builtin_nontemporal_load(&ei[E + i]);
    int s = __builtin_nontemporal_load(&ei[i]);
    int b = d >> 9;
    int r = atomicAdd(&h[b], 1);
    ebb[(size_t)base[b] + r] = (ull)(unsigned)s | ((ull)(unsigned)d << 32);
  }
}

// ---- 2a: per-bucket node degrees via LDS, coalesced writeout ----
__global__ void k_deg_bucket(const ull* __restrict__ ebb, const int* __restrict__ off,
                             int* __restrict__ deg, int E, int ntiles, int nb, int N) {
  __shared__ int cnt[512];
  const int b = blockIdx.x;
  for (int i = threadIdx.x; i < 512; i += 256) cnt[i] = 0;
  const int lo = off[(size_t)b * ntiles];
  const int hi = (b + 1 < nb) ? off[(size_t)(b + 1) * ntiles] : E;
  __syncthreads();
  for (int i = lo + threadIdx.x; i < hi; i += 256) {
    ull q = __builtin_nontemporal_load(&ebb[i]);
    atomicAdd(&cnt[(int)(q >> 32) - (b << 9)], 1);
  }
  __syncthreads();
  for (int i = threadIdx.x; i < 512; i += 256) {
    int v = (b << 9) + i;
    if (v < N) deg[v] = cnt[i];
  }
}

// ---------------- prefix sum (generic ITEMS per thread, <=256 parts) ----------------
template <int ITEMS>
__global__ void k_scan_part(const int* __restrict__ v, int* __restrict__ part, int n) {
  __shared__ int sd[256];
  int base = blockIdx.x * (256 * ITEMS) + threadIdx.x * ITEMS;
  int s = 0;
#pragma unroll
  for (int k = 0; k < ITEMS; k++) {
    int idx = base + k;
    if (idx < n) s += v[idx];
  }
  sd[threadIdx.x] = s;
  __syncthreads();
  for (int off = 128; off > 0; off >>= 1) {
    if (threadIdx.x < off) sd[threadIdx.x] += sd[threadIdx.x + off];
    __syncthreads();
  }
  if (threadIdx.x == 0) part[blockIdx.x] = sd[0];
}

__global__ void k_scan_offsets(int* __restrict__ part, int nparts,
                               int* __restrict__ outp, int n) {
  __shared__ int sd[256];
  int v = (threadIdx.x < nparts) ? part[threadIdx.x] : 0;
  sd[threadIdx.x] = v;
  __syncthreads();
  for (int off = 1; off < 256; off <<= 1) {
    int t = (threadIdx.x >= off) ? sd[threadIdx.x - off] : 0;
    __syncthreads();
    sd[threadIdx.x] += t;
    __syncthreads();
  }
  if (threadIdx.x < nparts) part[threadIdx.x] = sd[threadIdx.x] - v;  // exclusive
  if (threadIdx.x == 0) outp[n] = sd[255];                            // total
}

template <int ITEMS>
__global__ void k_scan_final(const int* __restrict__ v, const int* __restrict__ part,
                             int* __restrict__ outp, int n) {
  __shared__ int sd[256];
  int base = blockIdx.x * (256 * ITEMS) + threadIdx.x * ITEMS;
  int loc[ITEMS];
  int s = 0;
#pragma unroll
  for (int k = 0; k < ITEMS; k++) {
    int idx = base + k;
    loc[k] = (idx < n) ? v[idx] : 0;
    s += loc[k];
  }
  sd[threadIdx.x] = s;
  __syncthreads();
  for (int off = 1; off < 256; off <<= 1) {
    int t = (threadIdx.x >= off) ? sd[threadIdx.x - off] : 0;
    __syncthreads();
    sd[threadIdx.x] += t;
    __syncthreads();
  }
  int run = part[blockIdx.x] + sd[threadIdx.x] - s;  // exclusive offset
#pragma unroll
  for (int k = 0; k < ITEMS; k++) {
    int idx = base + k;
    if (idx < n) {
      outp[idx] = run;
      run += loc[k];
    }
  }
}

// dinv = rsqrt(in_deg + 1 self-loop)
__global__ void k_dinv(const int* __restrict__ deg, float* __restrict__ dinv, int n) {
  int i = blockIdx.x * blockDim.x + threadIdx.x;
  if (i < n) dinv[i] = rsqrtf((float)deg[i] + 1.0f);
}

// ---- 2b: fill csr; bucket's csr region is written by exactly ONE block ----
__global__ void k_fill_bucket(const ull* __restrict__ ebb, const int* __restrict__ off,
                              const int* __restrict__ rowptr, int* __restrict__ csr,
                              int E, int ntiles, int nb, int N) {
  __shared__ int cur[512];
  const int b = blockIdx.x;
  for (int i = threadIdx.x; i < 512; i += 256) {
    int v = (b << 9) + i;
    cur[i] = (v < N) ? rowptr[v] : 0;
  }
  const int lo = off[(size_t)b * ntiles];
  const int hi = (b + 1 < nb) ? off[(size_t)(b + 1) * ntiles] : E;
  __syncthreads();
  for (int i = lo + threadIdx.x; i < hi; i += 256) {
    ull q = __builtin_nontemporal_load(&ebb[i]);
    int s = (int)(unsigned)q;
    int dl = (int)(q >> 32) - (b << 9);
    int pos = atomicAdd(&cur[dl], 1);
    csr[pos] = s;
  }
}

// ---------------- MFMA GEMM: Th[n,128](fp16) = (A[n,128] @ W[128,128]) * dinv[row] ----
template <int HALF_IN>
__launch_bounds__(256, 2)
__global__ void k_gemm_mfma(const void* __restrict__ Av, const float* __restrict__ W,
                            const float* __restrict__ dinv, __half* __restrict__ Th, int n) {
  __shared__ _Float16 Al[128 * 136];
  __shared__ _Float16 Bl[128 * 136];
  const int tid = threadIdx.x;
  const int row0 = blockIdx.x * 128;

  if (HALF_IN) {
    const _Float16* A = (const _Float16*)Av;
    for (int i = tid; i < 2048; i += 256) {
      int r = i >> 4;
      int k8 = (i & 15) << 3;
      half8 v = {0, 0, 0, 0, 0, 0, 0, 0};
      if (row0 + r < n) v = *(const half8*)&A[(size_t)(row0 + r) * D + k8];
      *(half4v*)&Al[r * 136 + KPOS(k8)]     = (half4v){v[0], v[1], v[2], v[3]};
      *(half4v*)&Al[r * 136 + KPOS(k8 + 4)] = (half4v){v[4], v[5], v[6], v[7]};
    }
  } else {
    const float* A = (const float*)Av;
    for (int i = tid; i < 4096; i += 256) {
      int r = i >> 5;
      int k4 = (i & 31) << 2;
      float4 v = make_float4(0.f, 0.f, 0.f, 0.f);
      if (row0 + r < n) v = ((const float4*)A)[(size_t)(row0 + r) * 32 + (i & 31)];
      *(half4v*)&Al[r * 136 + KPOS(k4)] =
          (half4v){(_Float16)v.x, (_Float16)v.y, (_Float16)v.z, (_Float16)v.w};
    }
  }
  for (int i = tid; i < 4096; i += 256) {
    int c = i & 127;
    int k4 = (i >> 7) << 2;
    float w0 = W[(k4 + 0) * D + c];
    float w1 = W[(k4 + 1) * D + c];
    float w2 = W[(k4 + 2) * D + c];
    float w3 = W[(k4 + 3) * D + c];
    *(half4v*)&Bl[c * 136 + KPOS(k4)] =
        (half4v){(_Float16)w0, (_Float16)w1, (_Float16)w2, (_Float16)w3};
  }
  __syncthreads();

  const int w = tid >> 6;
  const int lane = tid & 63;
  const int g = lane >> 4;
  const int q = lane & 15;

  f32x4 acc[2][8];
#pragma unroll
  for (int mt = 0; mt < 2; mt++)
#pragma unroll
    for (int nt = 0; nt < 8; nt++) acc[mt][nt] = (f32x4){0.f, 0.f, 0.f, 0.f};

#pragma unroll
  for (int kt = 0; kt < 4; kt++) {
    half8 a[2], b[8];
#pragma unroll
    for (int mt = 0; mt < 2; mt++)
      a[mt] = *(const half8*)&Al[(w * 32 + mt * 16 + q) * 136 + kt * 32 + g * 8];
#pragma unroll
    for (int nt = 0; nt < 8; nt++)
      b[nt] = *(const half8*)&Bl[(nt * 16 + q) * 136 + kt * 32 + g * 8];
#pragma unroll
    for (int mt = 0; mt < 2; mt++)
#pragma unroll
      for (int nt = 0; nt < 8; nt++)
        acc[mt][nt] = __builtin_amdgcn_mfma_f32_16x16x32_f16(a[mt], b[nt], acc[mt][nt], 0, 0, 0);
  }

#pragma unroll
  for (int mt = 0; mt < 2; mt++) {
    int baseRow = row0 + w * 32 + mt * 16 + g * 4;
    float dv[4];
#pragma unroll
    for (int r = 0; r < 4; r++) dv[r] = (baseRow + r < n) ? dinv[baseRow + r] : 0.f;
#pragma unroll
    for (int nt = 0; nt < 8; nt++) {
      int col = nt * 16 + q;
#pragma unroll
      for (int r = 0; r < 4; r++) {
        int gr = baseRow + r;
        if (gr < n) Th[(size_t)gr * D + col] = (__half)(acc[mt][nt][r] * dv[r]);
      }
    }
  }
}

// ---------------- pull-style aggregation (fp16 gathers, unroll 8) ----------------
template <int MODE>
__launch_bounds__(256)
__global__ void k_aggregate(const int* __restrict__ rowptr, const int* __restrict__ csr,
                            const float* __restrict__ dinv, const __half* __restrict__ th,
                            const float* __restrict__ b, const __half* __restrict__ resh,
                            __half* __restrict__ outh, float* __restrict__ outf, int n) {
  int node = blockIdx.x * 16 + (threadIdx.x >> 4);
  if (node >= n) return;
  const int l16 = threadIdx.x & 15;

  int beg = rowptr[node];
  int end = rowptr[node + 1];
  float dd = dinv[node];

  const float4* t4 = (const float4*)th;

  float a0, a1, a2, a3, a4, a5, a6, a7;
  {
    float4 raw = t4[(size_t)node * 16 + l16];
    const __half2* hp = (const __half2*)&raw;
    float2 f0 = __half22float2(hp[0]);
    float2 f1 = __half22float2(hp[1]);
    float2 f2 = __half22float2(hp[2]);
    float2 f3 = __half22float2(hp[3]);
    a0 = f0.x; a1 = f0.y; a2 = f1.x; a3 = f1.y;
    a4 = f2.x; a5 = f2.y; a6 = f3.x; a7 = f3.y;
  }

#define ACC_ROW(raw)                                  \
  {                                                   \
    const __half2* hp = (const __half2*)&(raw);       \
    float2 f0 = __half22float2(hp[0]);                \
    float2 f1 = __half22float2(hp[1]);                \
    float2 f2 = __half22float2(hp[2]);                \
    float2 f3 = __half22float2(hp[3]);                \
    a0 += f0.x; a1 += f0.y; a2 += f1.x; a3 += f1.y;   \
    a4 += f2.x; a5 += f2.y; a6 += f3.x; a7 += f3.y;   \
  }

  int j = beg;
  for (; j + 8 <= end; j += 8) {
    float4 r0, r1, r2, r3, r4, r5, r6, r7;
    {
      int s0 = __builtin_nontemporal_load(&csr[j + 0]);
      int s1 = __builtin_nontemporal_load(&csr[j + 1]);
      int s2 = __builtin_nontemporal_load(&csr[j + 2]);
      int s3 = __builtin_nontemporal_load(&csr[j + 3]);
      int s4 = __builtin_nontemporal_load(&csr[j + 4]);
      int s5 = __builtin_nontemporal_load(&csr[j + 5]);
      int s6 = __builtin_nontemporal_load(&csr[j + 6]);
      int s7 = __builtin_nontemporal_load(&csr[j + 7]);
      r0 = t4[(size_t)(unsigned)s0 * 16 + l16];
      r1 = t4[(size_t)(unsigned)s1 * 16 + l16];
      r2 = t4[(size_t)(unsigned)s2 * 16 + l16];
      r3 = t4[(size_t)(unsigned)s3 * 16 + l16];
      r4 = t4[(size_t)(unsigned)s4 * 16 + l16];
      r5 = t4[(size_t)(unsigned)s5 * 16 + l16];
      r6 = t4[(size_t)(unsigned)s6 * 16 + l16];
      r7 = t4[(size_t)(unsigned)s7 * 16 + l16];
    }
    ACC_ROW(r0) ACC_ROW(r1) ACC_ROW(r2) ACC_ROW(r3)
    ACC_ROW(r4) ACC_ROW(r5) ACC_ROW(r6) ACC_ROW(r7)
  }
  for (; j + 4 <= end; j += 4) {
    int s0 = __builtin_nontemporal_load(&csr[j + 0]);
    int s1 = __builtin_nontemporal_load(&csr[j + 1]);
    int s2 = __builtin_nontemporal_load(&csr[j + 2]);
    int s3 = __builtin_nontemporal_load(&csr[j + 3]);
    float4 r0 = t4[(size_t)(unsigned)s0 * 16 + l16];
    float4 r1 = t4[(size_t)(unsigned)s1 * 16 + l16];
    float4 r2 = t4[(size_t)(unsigned)s2 * 16 + l16];
    float4 r3 = t4[(size_t)(unsigned)s3 * 16 + l16];
    ACC_ROW(r0) ACC_ROW(r1) ACC_ROW(r2) ACC_ROW(r3)
  }
  for (; j < end; ++j) {
    int s = __builtin_nontemporal_load(&csr[j]);
    float4 r = t4[(size_t)(unsigned)s * 16 + l16];
    ACC_ROW(r)
  }
#undef ACC_ROW

  const float4* b4 = (const float4*)b;
  float4 bb0 = b4[l16 * 2];
  float4 bb1 = b4[l16 * 2 + 1];
  float o0 = fmaf(a0, dd, bb0.x), o1 = fmaf(a1, dd, bb0.y);
  float o2 = fmaf(a2, dd, bb0.z), o3 = fmaf(a3, dd, bb0.w);
  float o4 = fmaf(a4, dd, bb1.x), o5 = fmaf(a5, dd, bb1.y);
  float o6 = fmaf(a6, dd, bb1.z), o7 = fmaf(a7, dd, bb1.w);

  if (MODE == 1) {
    float4 raw = ((const float4*)resh)[(size_t)node * 16 + l16];
    const __half2* hp = (const __half2*)&raw;
    float2 f0 = __half22float2(hp[0]);
    float2 f1 = __half22float2(hp[1]);
    float2 f2 = __half22float2(hp[2]);
    float2 f3 = __half22float2(hp[3]);
    o0 += f0.x; o1 += f0.y; o2 += f1.x; o3 += f1.y;
    o4 += f2.x; o5 += f2.y; o6 += f3.x; o7 += f3.y;
  }
  if (MODE == 0 || MODE == 1) {
    o0 = fmaxf(o0, 0.f); o1 = fmaxf(o1, 0.f); o2 = fmaxf(o2, 0.f); o3 = fmaxf(o3, 0.f);
    o4 = fmaxf(o4, 0.f); o5 = fmaxf(o5, 0.f); o6 = fmaxf(o6, 0.f); o7 = fmaxf(o7, 0.f);
    union { __half2 h[4]; float4 f; } pk;
    pk.h[0] = __floats2half2_rn(o0, o1);
    pk.h[1] = __floats2half2_rn(o2, o3);
    pk.h[2] = __floats2half2_rn(o4, o5);
    pk.h[3] = __floats2half2_rn(o6, o7);
    ((float4*)outh)[(size_t)node * 16 + l16] = pk.f;
  } else {
    ((float4*)outf)[(size_t)node * 32 + l16 * 2] = make_float4(o0, o1, o2, o3);
    ((float4*)outf)[(size_t)node * 32 + l16 * 2 + 1] = make_float4(o4, o5, o6, o7);
  }
}

extern "C" void kernel_launch(void* const* d_in, const int* in_sizes, int n_in,
                              void* d_out, int out_size, void* d_ws, size_t ws_size,
                              hipStream_t stream) {
  const float* x  = (const float*)d_in[0];
  const int*   ei = (const int*)d_in[1];
  const float* W0 = (const float*)d_in[2];
  const float* b0 = (const float*)d_in[3];
  const float* W1 = (const float*)d_in[4];
  const float* b1 = (const float*)d_in[5];
  const float* W2 = (const float*)d_in[6];
  const float* b2 = (const float*)d_in[7];
  float* out = (float*)d_out;

  const int N = in_sizes[0] / D;   // 100000
  const int E = in_sizes[1] / 2;   // 3200000

  const int ntiles = (E + TILE - 1) / TILE;   // 196
  const int nb = (N + 511) >> 9;              // 196 buckets of 512 nodes

  char* wsb = (char*)d_ws;
  auto alloc = [&](size_t bytes) {
    char* p = wsb;
    wsb += ((bytes + 255) & ~(size_t)255);
    return p;
  };
  int*    rowptr = (int*)alloc((N + 1) * 4);
  int*    deg    = (int*)alloc(N * 4);
  int*    part   = (int*)alloc(256 * 4);
  float*  dinv   = (float*)alloc(N * 4);
  int*    cnt    = (int*)alloc((size_t)nb * ntiles * 4);
  int*    off    = (int*)alloc((size_t)nb * ntiles * 4);
  ull*    ebb    = (ull*)alloc((size_t)E * 8);
  int*    csr    = (int*)alloc((size_t)E * 4);
  __half* th     = (__half*)alloc((size_t)N * D * 2);
  __half* g1h    = (__half*)alloc((size_t)N * D * 2);
  __half* g2h    = (__half*)alloc((size_t)N * D * 2);

  dim3 b256(256);
  int gN   = (N + 255) / 256;
  int gGem = (N + 127) / 128;
  int gAgg = (N + 15) / 16;
  int np1  = (N + 2047) / 2048;   // ITEMS=8 -> 49 parts

  // ---- CSR build: atomic-free two-level counting sort ----
  k_cnt_tiles<<<ntiles, b256, 0, stream>>>(ei + E, cnt, E, ntiles, nb);
  k_tile_scan<<<1, b256, 0, stream>>>(cnt, off, nb, ntiles);
  k_scatter_bucket<<<ntiles, b256, 0, stream>>>(ei, off, ebb, E, ntiles, nb);
  k_deg_bucket<<<nb, b256, 0, stream>>>(ebb, off, deg, E, ntiles, nb, N);
  k_scan_part<8><<<np1, b256, 0, stream>>>(deg, part, N);
  k_scan_offsets<<<1, b256, 0, stream>>>(part, np1, rowptr, N);
  k_scan_final<8><<<np1, b256, 0, stream>>>(deg, part, rowptr, N);
  k_dinv<<<gN, b256, 0, stream>>>(deg, dinv, N);
  k_fill_bucket<<<nb, b256, 0, stream>>>(ebb, off, rowptr, csr, E, ntiles, nb, N);

  // ---- layer 0: g1 = relu(Agg(x@W0) + b0)  [fp16] ----
  k_gemm_mfma<0><<<gGem, b256, 0, stream>>>(x, W0, dinv, th, N);
  k_aggregate<0><<<gAgg, b256, 0, stream>>>(rowptr, csr, dinv, th, b0, nullptr, g1h, nullptr, N);

  // ---- layer 1: h2 = relu(Agg(g1@W1) + b1 + g1)  [fp16] ----
  k_gemm_mfma<1><<<gGem, b256, 0, stream>>>(g1h, W1, dinv, th, N);
  k_aggregate<1><<<gAgg, b256, 0, stream>>>(rowptr, csr, dinv, th, b1, g1h, g2h, nullptr, N);

  // ---- layer 2: out = Agg(h2@W2) + b2  [f32 -> d_out] ----
  k_gemm_mfma<1><<<gGem, b256, 0, stream>>>(g2h, W2, dinv, th, N);
  k_aggregate<2><<<gAgg, b256, 0, stream>>>(rowptr, csr, dinv, th, b2, nullptr, nullptr, out, N);
}

// Round 14
// 665.352 us; speedup vs baseline: 1.2544x; 1.0004x over previous
//
#include <hip/hip_runtime.h>
#include <hip/hip_fp16.h>

#define D 128
#define TILE 16384
typedef unsigned long long ull;
typedef _Float16 half8 __attribute__((ext_vector_type(8)));
typedef _Float16 half4v __attribute__((ext_vector_type(4)));
typedef float f32x4 __attribute__((ext_vector_type(4)));

// k-permutation: quartet k4 -> LDS pos so each MFMA fragment is one ds_read_b128
#define KPOS(k4) (((k4) & ~31) + ((((k4) & 15) >> 2) << 3) + ((((k4) >> 4) & 1) << 2))

// ---- 1a: per-tile bucket histogram (bucket = dst>>9), LDS only ----
__global__ void k_cnt_tiles(const int* __restrict__ ei_dst, int* __restrict__ cnt,
                            int E, int ntiles, int nb) {
  __shared__ int h[256];
  for (int i = threadIdx.x; i < nb; i += 256) h[i] = 0;
  __syncthreads();
  const int t = blockIdx.x;
  const int start = t * TILE;
  int end = start + TILE;
  if (end > E) end = E;
  for (int i = start + threadIdx.x; i < end; i += 256)
    atomicAdd(&h[__builtin_nontemporal_load(&ei_dst[i]) >> 9], 1);
  __syncthreads();
  for (int b = threadIdx.x; b < nb; b += 256)
    cnt[(size_t)b * ntiles + t] = h[b];
}

// ---- 1b: off[b][t] = base(b) + prefix over tiles; single block, no atomics ----
__global__ void k_tile_scan(const int* __restrict__ cnt, int* __restrict__ off,
                            int nb, int ntiles) {
  __shared__ int sd[256];
  int total = 0;
  if (threadIdx.x < nb) {
    const int* row = cnt + (size_t)threadIdx.x * ntiles;
    for (int t = 0; t < ntiles; t++) total += row[t];
  }
  sd[threadIdx.x] = total;
  __syncthreads();
  for (int o = 1; o < 256; o <<= 1) {
    int v = (threadIdx.x >= o) ? sd[threadIdx.x - o] : 0;
    __syncthreads();
    sd[threadIdx.x] += v;
    __syncthreads();
  }
  int base = sd[threadIdx.x] - total;  // exclusive
  if (threadIdx.x < nb) {
    const int* row = cnt + (size_t)threadIdx.x * ntiles;
    int* orow = off + (size_t)threadIdx.x * ntiles;
    int run = base;
    for (int t = 0; t < ntiles; t++) { orow[t] = run; run += row[t]; }
  }
}

// ---- 1c: scatter edges into bucket-major runs (LDS rank, no global atomics) ----
__global__ void k_scatter_bucket(const int* __restrict__ ei, const int* __restrict__ off,
                                 ull* __restrict__ ebb, int E, int ntiles, int nb) {
  __shared__ int h[256];
  __shared__ int base[256];
  const int t = blockIdx.x;
  for (int i = threadIdx.x; i < nb; i += 256) {
    h[i] = 0;
    base[i] = off[(size_t)i * ntiles + t];
  }
  __syncthreads();
  const int start = t * TILE;
  int end = start + TILE;
  if (end > E) end = E;
  for (int i = start + threadIdx.x; i < end; i += 256) {
    int d = __builtin_nontemporal_load(&ei[E + i]);
    int s = __builtin_nontemporal_load(&ei[i]);
    int b = d >> 9;
    int r = atomicAdd(&h[b], 1);
    ebb[(size_t)base[b] + r] = (ull)(unsigned)s | ((ull)(unsigned)d << 32);
  }
}

// ---- 2: fused per-bucket {degree count, LDS scan -> rowptr/dinv/cursor, fill} ----
// csr is globally dst-sorted, so bucket base rowptr == off[b][0]; no global scan.
__global__ void k_fill_bucket2(const ull* __restrict__ ebb, const int* __restrict__ off,
                               int* __restrict__ rowptr, float* __restrict__ dinv,
                               int* __restrict__ csr, int E, int ntiles, int nb, int N) {
  __shared__ int cnt[512];   // counts, then cursors
  __shared__ int ps[256];
  const int b = blockIdx.x;
  const int tid = threadIdx.x;
  const int lo = off[(size_t)b * ntiles];
  const int hi = (b + 1 < nb) ? off[(size_t)(b + 1) * ntiles] : E;
  for (int i = tid; i < 512; i += 256) cnt[i] = 0;
  __syncthreads();
  // pass 1: bucket-local degree histogram
  for (int i = lo + tid; i < hi; i += 256) {
    ull q = __builtin_nontemporal_load(&ebb[i]);
    atomicAdd(&cnt[(int)(q >> 32) - (b << 9)], 1);
  }
  __syncthreads();
  // LDS scan over 512 entries (2 per thread)
  int c0 = cnt[2 * tid];
  int c1 = cnt[2 * tid + 1];
  int pair = c0 + c1;
  ps[tid] = pair;
  __syncthreads();
  for (int o = 1; o < 256; o <<= 1) {
    int v = (tid >= o) ? ps[tid - o] : 0;
    __syncthreads();
    ps[tid] += v;
    __syncthreads();
  }
  int base0 = lo + ps[tid] - pair;   // exclusive offset of node 2*tid
  int v0 = (b << 9) + 2 * tid;
  int v1 = v0 + 1;
  if (v0 < N) {
    rowptr[v0] = base0;
    dinv[v0] = rsqrtf((float)c0 + 1.0f);
  }
  if (v1 < N) {
    rowptr[v1] = base0 + c0;
    dinv[v1] = rsqrtf((float)c1 + 1.0f);
  }
  if (b == 0 && tid == 0) rowptr[N] = E;
  cnt[2 * tid] = base0;          // cursors (reads of cnt done above)
  cnt[2 * tid + 1] = base0 + c0;
  __syncthreads();
  // pass 2: fill (ebb chunk ~130KB is L2-resident from pass 1)
  for (int i = lo + tid; i < hi; i += 256) {
    ull q = __builtin_nontemporal_load(&ebb[i]);
    int s = (int)(unsigned)q;
    int dl = (int)(q >> 32) - (b << 9);
    int pos = atomicAdd(&cnt[dl], 1);
    csr[pos] = s;
  }
}

// ---------------- MFMA GEMM: Th[n,128](fp16) = (A[n,128] @ W[128,128]) * dinv[row] ----
template <int HALF_IN>
__launch_bounds__(256, 2)
__global__ void k_gemm_mfma(const void* __restrict__ Av, const float* __restrict__ W,
                            const float* __restrict__ dinv, __half* __restrict__ Th, int n) {
  __shared__ _Float16 Al[128 * 136];
  __shared__ _Float16 Bl[128 * 136];
  const int tid = threadIdx.x;
  const int row0 = blockIdx.x * 128;

  if (HALF_IN) {
    const _Float16* A = (const _Float16*)Av;
    for (int i = tid; i < 2048; i += 256) {
      int r = i >> 4;
      int k8 = (i & 15) << 3;
      half8 v = {0, 0, 0, 0, 0, 0, 0, 0};
      if (row0 + r < n) v = *(const half8*)&A[(size_t)(row0 + r) * D + k8];
      *(half4v*)&Al[r * 136 + KPOS(k8)]     = (half4v){v[0], v[1], v[2], v[3]};
      *(half4v*)&Al[r * 136 + KPOS(k8 + 4)] = (half4v){v[4], v[5], v[6], v[7]};
    }
  } else {
    const float* A = (const float*)Av;
    for (int i = tid; i < 4096; i += 256) {
      int r = i >> 5;
      int k4 = (i & 31) << 2;
      float4 v = make_float4(0.f, 0.f, 0.f, 0.f);
      if (row0 + r < n) v = ((const float4*)A)[(size_t)(row0 + r) * 32 + (i & 31)];
      *(half4v*)&Al[r * 136 + KPOS(k4)] =
          (half4v){(_Float16)v.x, (_Float16)v.y, (_Float16)v.z, (_Float16)v.w};
    }
  }
  for (int i = tid; i < 4096; i += 256) {
    int c = i & 127;
    int k4 = (i >> 7) << 2;
    float w0 = W[(k4 + 0) * D + c];
    float w1 = W[(k4 + 1) * D + c];
    float w2 = W[(k4 + 2) * D + c];
    float w3 = W[(k4 + 3) * D + c];
    *(half4v*)&Bl[c * 136 + KPOS(k4)] =
        (half4v){(_Float16)w0, (_Float16)w1, (_Float16)w2, (_Float16)w3};
  }
  __syncthreads();

  const int w = tid >> 6;
  const int lane = tid & 63;
  const int g = lane >> 4;
  const int q = lane & 15;

  f32x4 acc[2][8];
#pragma unroll
  for (int mt = 0; mt < 2; mt++)
#pragma unroll
    for (int nt = 0; nt < 8; nt++) acc[mt][nt] = (f32x4){0.f, 0.f, 0.f, 0.f};

#pragma unroll
  for (int kt = 0; kt < 4; kt++) {
    half8 a[2], bb[8];
#pragma unroll
    for (int mt = 0; mt < 2; mt++)
      a[mt] = *(const half8*)&Al[(w * 32 + mt * 16 + q) * 136 + kt * 32 + g * 8];
#pragma unroll
    for (int nt = 0; nt < 8; nt++)
      bb[nt] = *(const half8*)&Bl[(nt * 16 + q) * 136 + kt * 32 + g * 8];
#pragma unroll
    for (int mt = 0; mt < 2; mt++)
#pragma unroll
      for (int nt = 0; nt < 8; nt++)
        acc[mt][nt] = __builtin_amdgcn_mfma_f32_16x16x32_f16(a[mt], bb[nt], acc[mt][nt], 0, 0, 0);
  }

#pragma unroll
  for (int mt = 0; mt < 2; mt++) {
    int baseRow = row0 + w * 32 + mt * 16 + g * 4;
    float dv[4];
#pragma unroll
    for (int r = 0; r < 4; r++) dv[r] = (baseRow + r < n) ? dinv[baseRow + r] : 0.f;
#pragma unroll
    for (int nt = 0; nt < 8; nt++) {
      int col = nt * 16 + q;
#pragma unroll
      for (int r = 0; r < 4; r++) {
        int gr = baseRow + r;
        if (gr < n) Th[(size_t)gr * D + col] = (__half)(acc[mt][nt][r] * dv[r]);
      }
    }
  }
}

// ---------------- pull-style aggregation (fp16 gathers, unroll 8, grid-stride) ----------------
// th pre-scaled by dinv[row]:  acc = dinv[d]*(th[d] + sum th[src]) + b  [+res] [relu]
// 16 lanes per node (lane owns 8 cols = 16B fp16); grid-stride over nodes.
template <int MODE>
__launch_bounds__(256)
__global__ void k_aggregate(const int* __restrict__ rowptr, const int* __restrict__ csr,
                            const float* __restrict__ dinv, const __half* __restrict__ th,
                            const float* __restrict__ b, const __half* __restrict__ resh,
                            __half* __restrict__ outh, float* __restrict__ outf, int n) {
  const int g = threadIdx.x >> 4;
  const int l16 = threadIdx.x & 15;
  const float4* t4 = (const float4*)th;
  const float4* b4 = (const float4*)b;
  float4 bb0 = b4[l16 * 2];
  float4 bb1 = b4[l16 * 2 + 1];

  for (int node = blockIdx.x * 16 + g; node < n; node += gridDim.x * 16) {
    int beg = rowptr[node];
    int end = rowptr[node + 1];
    float dd = dinv[node];

    float a0, a1, a2, a3, a4, a5, a6, a7;
    {
      float4 raw = t4[(size_t)node * 16 + l16];   // self term
      const __half2* hp = (const __half2*)&raw;
      float2 f0 = __half22float2(hp[0]);
      float2 f1 = __half22float2(hp[1]);
      float2 f2 = __half22float2(hp[2]);
      float2 f3 = __half22float2(hp[3]);
      a0 = f0.x; a1 = f0.y; a2 = f1.x; a3 = f1.y;
      a4 = f2.x; a5 = f2.y; a6 = f3.x; a7 = f3.y;
    }

#define ACC_ROW(raw)                                  \
  {                                                   \
    const __half2* hp = (const __half2*)&(raw);       \
    float2 f0 = __half22float2(hp[0]);                \
    float2 f1 = __half22float2(hp[1]);                \
    float2 f2 = __half22float2(hp[2]);                \
    float2 f3 = __half22float2(hp[3]);                \
    a0 += f0.x; a1 += f0.y; a2 += f1.x; a3 += f1.y;   \
    a4 += f2.x; a5 += f2.y; a6 += f3.x; a7 += f3.y;   \
  }

    int j = beg;
    for (; j + 8 <= end; j += 8) {
      float4 r0, r1, r2, r3, r4, r5, r6, r7;
      {
        int s0 = __builtin_nontemporal_load(&csr[j + 0]);
        int s1 = __builtin_nontemporal_load(&csr[j + 1]);
        int s2 = __builtin_nontemporal_load(&csr[j + 2]);
        int s3 = __builtin_nontemporal_load(&csr[j + 3]);
        int s4 = __builtin_nontemporal_load(&csr[j + 4]);
        int s5 = __builtin_nontemporal_load(&csr[j + 5]);
        int s6 = __builtin_nontemporal_load(&csr[j + 6]);
        int s7 = __builtin_nontemporal_load(&csr[j + 7]);
        r0 = t4[(size_t)(unsigned)s0 * 16 + l16];
        r1 = t4[(size_t)(unsigned)s1 * 16 + l16];
        r2 = t4[(size_t)(unsigned)s2 * 16 + l16];
        r3 = t4[(size_t)(unsigned)s3 * 16 + l16];
        r4 = t4[(size_t)(unsigned)s4 * 16 + l16];
        r5 = t4[(size_t)(unsigned)s5 * 16 + l16];
        r6 = t4[(size_t)(unsigned)s6 * 16 + l16];
        r7 = t4[(size_t)(unsigned)s7 * 16 + l16];
      }
      ACC_ROW(r0) ACC_ROW(r1) ACC_ROW(r2) ACC_ROW(r3)
      ACC_ROW(r4) ACC_ROW(r5) ACC_ROW(r6) ACC_ROW(r7)
    }
    for (; j + 4 <= end; j += 4) {
      int s0 = __builtin_nontemporal_load(&csr[j + 0]);
      int s1 = __builtin_nontemporal_load(&csr[j + 1]);
      int s2 = __builtin_nontemporal_load(&csr[j + 2]);
      int s3 = __builtin_nontemporal_load(&csr[j + 3]);
      float4 r0 = t4[(size_t)(unsigned)s0 * 16 + l16];
      float4 r1 = t4[(size_t)(unsigned)s1 * 16 + l16];
      float4 r2 = t4[(size_t)(unsigned)s2 * 16 + l16];
      float4 r3 = t4[(size_t)(unsigned)s3 * 16 + l16];
      ACC_ROW(r0) ACC_ROW(r1) ACC_ROW(r2) ACC_ROW(r3)
    }
    for (; j < end; ++j) {
      int s = __builtin_nontemporal_load(&csr[j]);
      float4 r = t4[(size_t)(unsigned)s * 16 + l16];
      ACC_ROW(r)
    }
#undef ACC_ROW

    float o0 = fmaf(a0, dd, bb0.x), o1 = fmaf(a1, dd, bb0.y);
    float o2 = fmaf(a2, dd, bb0.z), o3 = fmaf(a3, dd, bb0.w);
    float o4 = fmaf(a4, dd, bb1.x), o5 = fmaf(a5, dd, bb1.y);
    float o6 = fmaf(a6, dd, bb1.z), o7 = fmaf(a7, dd, bb1.w);

    if (MODE == 1) {
      float4 raw = ((const float4*)resh)[(size_t)node * 16 + l16];
      const __half2* hp = (const __half2*)&raw;
      float2 f0 = __half22float2(hp[0]);
      float2 f1 = __half22float2(hp[1]);
      float2 f2 = __half22float2(hp[2]);
      float2 f3 = __half22float2(hp[3]);
      o0 += f0.x; o1 += f0.y; o2 += f1.x; o3 += f1.y;
      o4 += f2.x; o5 += f2.y; o6 += f3.x; o7 += f3.y;
    }
    if (MODE == 0 || MODE == 1) {
      o0 = fmaxf(o0, 0.f); o1 = fmaxf(o1, 0.f); o2 = fmaxf(o2, 0.f); o3 = fmaxf(o3, 0.f);
      o4 = fmaxf(o4, 0.f); o5 = fmaxf(o5, 0.f); o6 = fmaxf(o6, 0.f); o7 = fmaxf(o7, 0.f);
      union { __half2 h[4]; float4 f; } pk;
      pk.h[0] = __floats2half2_rn(o0, o1);
      pk.h[1] = __floats2half2_rn(o2, o3);
      pk.h[2] = __floats2half2_rn(o4, o5);
      pk.h[3] = __floats2half2_rn(o6, o7);
      ((float4*)outh)[(size_t)node * 16 + l16] = pk.f;
    } else {
      ((float4*)outf)[(size_t)node * 32 + l16 * 2] = make_float4(o0, o1, o2, o3);
      ((float4*)outf)[(size_t)node * 32 + l16 * 2 + 1] = make_float4(o4, o5, o6, o7);
    }
  }
}

extern "C" void kernel_launch(void* const* d_in, const int* in_sizes, int n_in,
                              void* d_out, int out_size, void* d_ws, size_t ws_size,
                              hipStream_t stream) {
  const float* x  = (const float*)d_in[0];
  const int*   ei = (const int*)d_in[1];
  const float* W0 = (const float*)d_in[2];
  const float* b0 = (const float*)d_in[3];
  const float* W1 = (const float*)d_in[4];
  const float* b1 = (const float*)d_in[5];
  const float* W2 = (const float*)d_in[6];
  const float* b2 = (const float*)d_in[7];
  float* out = (float*)d_out;

  const int N = in_sizes[0] / D;   // 100000
  const int E = in_sizes[1] / 2;   // 3200000

  const int ntiles = (E + TILE - 1) / TILE;   // 196
  const int nb = (N + 511) >> 9;              // 196 buckets of 512 nodes

  char* wsb = (char*)d_ws;
  auto alloc = [&](size_t bytes) {
    char* p = wsb;
    wsb += ((bytes + 255) & ~(size_t)255);
    return p;
  };
  int*    rowptr = (int*)alloc((N + 1) * 4);
  float*  dinv   = (float*)alloc(N * 4);
  int*    cnt    = (int*)alloc((size_t)nb * ntiles * 4);
  int*    off    = (int*)alloc((size_t)nb * ntiles * 4);
  ull*    ebb    = (ull*)alloc((size_t)E * 8);
  int*    csr    = (int*)alloc((size_t)E * 4);
  __half* th     = (__half*)alloc((size_t)N * D * 2);
  __half* g1h    = (__half*)alloc((size_t)N * D * 2);
  __half* g2h    = (__half*)alloc((size_t)N * D * 2);

  dim3 b256(256);
  int gGem = (N + 127) / 128;
  int gAgg = 2048;                 // grid-stride (G11: memory-bound cap)

  // ---- CSR build: atomic-free two-level counting sort (4 kernels) ----
  k_cnt_tiles<<<ntiles, b256, 0, stream>>>(ei + E, cnt, E, ntiles, nb);
  k_tile_scan<<<1, b256, 0, stream>>>(cnt, off, nb, ntiles);
  k_scatter_bucket<<<ntiles, b256, 0, stream>>>(ei, off, ebb, E, ntiles, nb);
  k_fill_bucket2<<<nb, b256, 0, stream>>>(ebb, off, rowptr, dinv, csr, E, ntiles, nb, N);

  // ---- layer 0: g1 = relu(Agg(x@W0) + b0)  [fp16] ----
  k_gemm_mfma<0><<<gGem, b256, 0, stream>>>(x, W0, dinv, th, N);
  k_aggregate<0><<<gAgg, b256, 0, stream>>>(rowptr, csr, dinv, th, b0, nullptr, g1h, nullptr, N);

  // ---- layer 1: h2 = relu(Agg(g1@W1) + b1 + g1)  [fp16] ----
  k_gemm_mfma<1><<<gGem, b256, 0, stream>>>(g1h, W1, dinv, th, N);
  k_aggregate<1><<<gAgg, b256, 0, stream>>>(rowptr, csr, dinv, th, b1, g1h, g2h, nullptr, N);

  // ---- layer 2: out = Agg(h2@W2) + b2  [f32 -> d_out] ----
  k_gemm_mfma<1><<<gGem, b256, 0, stream>>>(g2h, W2, dinv, th, N);
  k_aggregate<2><<<gAgg, b256, 0, stream>>>(rowptr, csr, dinv, th, b2, nullptr, nullptr, out, N);
}